// Round 16
// baseline (89.165 us; speedup 1.0000x reference)
//
#include <hip/hip_runtime.h>

typedef _Float16 half_t;
typedef _Float16 halfv8 __attribute__((ext_vector_type(8)));
typedef _Float16 halfv4 __attribute__((ext_vector_type(4)));
typedef float    floatv4 __attribute__((ext_vector_type(4)));
typedef unsigned int uint;
typedef uint uintv4 __attribute__((ext_vector_type(4)));

#define NODES 32
#define FIN   128
#define EPG   512
#define NBS   4096
#define ETOT  (NBS*EPG)
#define HID   1024
#define KDIM  4096          // FIN*NODES
#define NCLS  10
#define YP    34            // pitch (halves) for Z^T / H^T bounce (aliased in Ws)
#define WP    140           // pitch (halves) for W in LDS

// lin1 GEMM geometry
#define BM 256
#define BN 256
#define BK 64
#define KS 4
#define KSLEN (KDIM/KS)  // 1024
#define NT (KSLEN/BK)    // 16 K-tiles

#define GLDS16(g, l)                                                        \
  __builtin_amdgcn_global_load_lds(                                         \
      (const __attribute__((address_space(1))) unsigned int*)(g),           \
      (__attribute__((address_space(3))) unsigned int*)(l), 16, 0, 0)

// LDS index maps (halves). A layout: [r>>7][ (r>>6)&1 ][r&63][chunk^(r&7)]
__device__ __forceinline__ int aidx(int r, int cc) {
  return (r >> 7) * 8192 + ((r >> 6) & 1) * 4096 + (r & 63) * 64 +
         ((cc ^ (r & 7)) * 8);
}
// B layout: [r>>7][ (r>>5)&1 ][ (r>>6)&1 ][r&31][chunk^(r&7)]
__device__ __forceinline__ int bidx(int r, int cc) {
  return (r >> 7) * 8192 + ((r >> 5) & 1) * 4096 + ((r >> 6) & 1) * 2048 +
         (r & 31) * 64 + ((cc ^ (r & 7)) * 8);
}

// ---------------------------------------------------------------------------
// prep: pure fp32->fp16 casts (H layout [g][o*32+m] matches original w1).
__global__ __launch_bounds__(256) void prep_cvt(const float* __restrict__ w1,
                                                half_t* __restrict__ w1p,
                                                const float* __restrict__ gw,
                                                half_t* __restrict__ gw16) {
  const size_t q = (size_t)blockIdx.x * 256 + threadIdx.x;  // 1052672 quads
  const float* s;
  half_t* d;
  size_t off;
  if (q < 1048576) { s = w1; d = w1p; off = q; }
  else             { s = gw; d = gw16; off = q - 1048576; }
  floatv4 v = *(const floatv4*)(s + off * 4);
  halfv4 h = {(half_t)v[0], (half_t)v[1], (half_t)v[2], (half_t)v[3]};
  *(halfv4*)(d + off * 4) = h;
}

// ---------------------------------------------------------------------------
// gin_fused v9: v6 math, but Yt ALIASES Ws (Ws dead after MFMA1; one extra
// __syncthreads separates last Ws read from first Yt write). LDS 44 KB ->
// 3 blocks/CU for +50% latency hiding on the x/edge gathers.
__global__ __launch_bounds__(256, 3) void gin_fused(
    const float* __restrict__ x, const int* __restrict__ ei,
    const half_t* __restrict__ gw16, const float* __restrict__ gb,
    half_t* __restrict__ H) {
  __shared__ __attribute__((aligned(16))) half_t WsY[FIN * WP];  // 35840 B
  __shared__ uint cnt[4][512];                                   //  8192 B
  // total 44032 B -> 3 blocks/CU

  const int t = threadIdx.x, w = t >> 6, l = t & 63;
  const int lr = l & 15, lk = l >> 4;
  const int g = blockIdx.x * 4 + w;

  // (a) x tile (32x128 fp32) -> registers, batch-issued
  const float* xg = x + (size_t)g * (NODES * FIN);
  floatv4 xr[2][4][2];
#pragma unroll
  for (int mt = 0; mt < 2; ++mt)
#pragma unroll
    for (int kk = 0; kk < 4; ++kk) {
      const float* p = xg + (mt * 16 + lr) * FIN + kk * 32 + lk * 8;
      xr[mt][kk][0] = *(const floatv4*)p;
      xr[mt][kk][1] = *(const floatv4*)(p + 4);
    }

  // (b) stage W into LDS, coalesced halfv8 chunks
  {
    const halfv8* gsrc = (const halfv8*)gw16;
#pragma unroll
    for (int i = 0; i < 8; ++i) {
      const int c = i * 256 + t;
      const int o = c >> 4, f8 = c & 15;
      *(halfv8*)&WsY[o * WP + f8 * 8] = gsrc[c];
    }
  }

  // (c) edges
  const int* sp = ei + (size_t)g * EPG;
  const int* dp = ei + (size_t)ETOT + (size_t)g * EPG;
  uintv4 s0 = *(const uintv4*)(sp + l * 8);
  uintv4 s1 = *(const uintv4*)(sp + l * 8 + 4);
  uintv4 d0 = *(const uintv4*)(dp + l * 8);
  uintv4 d1 = *(const uintv4*)(dp + l * 8 + 4);

  // (d) wave-private histogram
  {
    uintv4* c4 = (uintv4*)cnt[w];
    uintv4 z = {0, 0, 0, 0};
    c4[l] = z;
    c4[l + 64] = z;
  }
#pragma unroll
  for (int q = 0; q < 4; ++q) {
    uint p0 = (d0[q] & 31) * 32 + (s0[q] & 31);
    atomicAdd(&cnt[w][p0 >> 1], 1u << ((p0 & 1) * 16));
    uint p1 = (d1[q] & 31) * 32 + (s1[q] & 31);
    atomicAdd(&cnt[w][p1 >> 1], 1u << ((p1 & 1) * 16));
  }

  // (e) x -> fp16 A-fragments
  halfv8 af[2][4];
#pragma unroll
  for (int mt = 0; mt < 2; ++mt)
#pragma unroll
    for (int kk = 0; kk < 4; ++kk) {
      halfv8 h;
#pragma unroll
      for (int q = 0; q < 4; ++q) {
        h[q]     = (half_t)xr[mt][kk][0][q];
        h[q + 4] = (half_t)xr[mt][kk][1][q];
      }
      af[mt][kk] = h;
    }

  __syncthreads();   // Ws staged (cross-wave)

  // (f) MFMA1: Z[j][o] = sum_f x[j][f] W[o][f]
  floatv4 acc[2][8] = {};
#pragma unroll
  for (int kk = 0; kk < 4; ++kk) {
    halfv8 bfk[8];
#pragma unroll
    for (int nt = 0; nt < 8; ++nt)
      bfk[nt] = *(const halfv8*)&WsY[(nt * 16 + lr) * WP + kk * 32 + lk * 8];
#pragma unroll
    for (int nt = 0; nt < 8; ++nt)
#pragma unroll
      for (int mt = 0; mt < 2; ++mt)
        acc[mt][nt] = __builtin_amdgcn_mfma_f32_16x16x32_f16(af[mt][kk], bfk[nt],
                                                             acc[mt][nt], 0, 0, 0);
  }

  __syncthreads();   // ALL waves done reading Ws -> safe to overlay Yt
  __builtin_amdgcn_sched_barrier(0);

  // (g) bounce Z^T into aliased per-wave Yt rows
  half_t* yw = WsY + w * (FIN * YP);
#pragma unroll
  for (int mt = 0; mt < 2; ++mt)
#pragma unroll
    for (int nt = 0; nt < 8; ++nt) {
      halfv4 h = {(half_t)acc[mt][nt][0], (half_t)acc[mt][nt][1],
                  (half_t)acc[mt][nt][2], (half_t)acc[mt][nt][3]};
      *(halfv4*)&yw[(nt * 16 + lr) * YP + mt * 16 + lk * 4] = h;
    }

  // (h) M' = I + C fragments from histogram
  const unsigned short* c16 = (const unsigned short*)cnt[w];
  halfv8 am[2];
#pragma unroll
  for (int mt = 0; mt < 2; ++mt) {
    const int i = mt * 16 + lr;
#pragma unroll
    for (int q = 0; q < 8; ++q) {
      const int j = lk * 8 + q;
      float c = (float)c16[i * 32 + j] + ((j == i) ? 1.f : 0.f);
      am[mt][q] = (half_t)c;
    }
  }

  // (i) MFMA2: H[i][o] = sum_j M'[i][j] Z[j][o]
  floatv4 acc2[2][8] = {};
#pragma unroll
  for (int nt = 0; nt < 8; ++nt) {
    halfv8 bf = *(const halfv8*)&yw[(nt * 16 + lr) * YP + lk * 8];
#pragma unroll
    for (int mt = 0; mt < 2; ++mt)
      acc2[mt][nt] = __builtin_amdgcn_mfma_f32_16x16x32_f16(am[mt], bf,
                                                            acc2[mt][nt], 0, 0, 0);
  }
  __builtin_amdgcn_sched_barrier(0);   // keep H^T writes below all Z^T reads

  // (j) bias + relu; overwrite with H^T[o][m]
#pragma unroll
  for (int nt = 0; nt < 8; ++nt) {
    const float bias = gb[nt * 16 + lr];
#pragma unroll
    for (int mt = 0; mt < 2; ++mt) {
      halfv4 h;
#pragma unroll
      for (int q = 0; q < 4; ++q) {
        const float v = acc2[mt][nt][q] + bias;
        h[q] = (half_t)(v > 0.f ? v : 0.f);
      }
      *(halfv4*)&yw[(nt * 16 + lr) * YP + mt * 16 + lk * 4] = h;
    }
  }
  __builtin_amdgcn_sched_barrier(0);

  // (k) linear readback -> fat coalesced stores: H[g][o*32+m], 1KB/instr
  half_t* Hg = H + (size_t)g * KDIM;
#pragma unroll
  for (int c = 0; c < 8; ++c) {
    const int ch = c * 64 + l;
    const int o = ch >> 2, m0 = (ch & 3) * 8;
    halfv8 v = *(const halfv8*)&yw[o * YP + m0];
    *(halfv8*)(Hg + ch * 8) = v;
  }
}

// ---------------------------------------------------------------------------
// lin1 GEMM: quadrant-phase pipeline (r15-proven, 38.7 us). Delta: removed
// the blunt asm lgkmcnt(0) fences -- compiler emits precise per-operand
// lgkmcnt(N) before each MFMA; ds-reads are consumed in-phase so they drain
// before each barrier naturally. Gates/barriers/setprio unchanged.
__global__ __launch_bounds__(512, 2) void lin1_gemm(
    const half_t* __restrict__ A, const half_t* __restrict__ B,
    half_t* __restrict__ Cbase) {
  __shared__ __attribute__((aligned(16))) half_t As[2][16384];  // 64 KB
  __shared__ __attribute__((aligned(16))) half_t Bs[2][16384];  // 64 KB

  const int t = threadIdx.x;
  const int orig = blockIdx.x;                     // 256 blocks, 1/CU
  const int wg = (orig & 7) * 32 + (orig >> 3);    // bijective XCD swizzle
  const int mt = wg & 15, rest = wg >> 4;
  const int nt_ = rest & 3, ksz = rest >> 2;
  const int m0 = mt * BM, n0 = nt_ * BN, k0 = ksz * KSLEN;

  const int csw = ((t & 7) ^ ((t >> 3) & 7)) * 8;
  const int ar0 = t >> 3;
  const int brl = (t >> 3) & 31, bg = t >> 8;
  const half_t* pA[2][2];
  const half_t* pB[2][2];
#pragma unroll
  for (int h = 0; h < 2; ++h) {
    pA[h][0] = A + (size_t)(m0 + ar0 + h * 64) * KDIM + k0 + csw;
    pA[h][1] = pA[h][0] + (size_t)128 * KDIM;
    pB[h][0] = B + (size_t)(n0 + bg * 64 + h * 32 + brl) * KDIM + k0 + csw;
    pB[h][1] = pB[h][0] + (size_t)128 * KDIM;
  }

#define STG_A(buf, h, kt_)                                                   \
  { GLDS16(pA[h][0] + (kt_) * BK, &As[buf][(h) * 4096 + t * 8]);             \
    GLDS16(pA[h][1] + (kt_) * BK, &As[buf][8192 + (h) * 4096 + t * 8]); }
#define STG_B(buf, h, kt_)                                                   \
  { GLDS16(pB[h][0] + (kt_) * BK, &Bs[buf][(h) * 4096 + t * 8]);             \
    GLDS16(pB[h][1] + (kt_) * BK, &Bs[buf][8192 + (h) * 4096 + t * 8]); }

  const int w = t >> 6, l = t & 63, lr = l & 15, lk = l >> 4;
  const int wm = (w >> 2) * 128, wn = (w & 3) * 64;

  floatv4 acc[8][4] = {};

  STG_A(0, 0, 0) STG_B(0, 0, 0) STG_B(0, 1, 0) STG_A(0, 1, 0)
  asm volatile("s_waitcnt vmcnt(4)" ::: "memory");
  __builtin_amdgcn_s_barrier();
  __builtin_amdgcn_sched_barrier(0);

  for (int kt = 0; kt < NT; ++kt) {
    const int cur = kt & 1, nxt = cur ^ 1;
    const int ktn = (kt + 1 < NT) ? (kt + 1) : 0;
    halfv8 af[4][2], bfL[2][2], bfH[2][2];

    // ======== Q0: rows wm..+63 x cols wn..+31 ========
#pragma unroll
    for (int mf = 0; mf < 4; ++mf)
#pragma unroll
      for (int ks = 0; ks < 2; ++ks)
        af[mf][ks] = *(const halfv8*)&As[cur][aidx(wm + mf * 16 + lr, ks * 4 + lk)];
#pragma unroll
    for (int nf = 0; nf < 2; ++nf)
#pragma unroll
      for (int ks = 0; ks < 2; ++ks)
        bfL[nf][ks] = *(const halfv8*)&Bs[cur][bidx(wn + nf * 16 + lr, ks * 4 + lk)];
    STG_A(nxt, 0, ktn)
    __builtin_amdgcn_s_barrier();
    __builtin_amdgcn_s_setprio(1);
#pragma unroll
    for (int mf = 0; mf < 4; ++mf)
#pragma unroll
      for (int nf = 0; nf < 2; ++nf)
#pragma unroll
        for (int ks = 0; ks < 2; ++ks)
          acc[mf][nf] = __builtin_amdgcn_mfma_f32_16x16x32_f16(
              af[mf][ks], bfL[nf][ks], acc[mf][nf], 0, 0, 0);
    __builtin_amdgcn_s_setprio(0);
    asm volatile("s_waitcnt vmcnt(4)" ::: "memory");  // gate Q1's bfH
    __builtin_amdgcn_s_barrier();
    __builtin_amdgcn_sched_barrier(0);

    // ======== Q1: rows wm..+63 x cols wn+32..+63 ========
#pragma unroll
    for (int nf = 0; nf < 2; ++nf)
#pragma unroll
      for (int ks = 0; ks < 2; ++ks)
        bfH[nf][ks] = *(const halfv8*)&Bs[cur][bidx(wn + 32 + nf * 16 + lr, ks * 4 + lk)];
    STG_B(nxt, 0, ktn)
    __builtin_amdgcn_s_barrier();
    __builtin_amdgcn_s_setprio(1);
#pragma unroll
    for (int mf = 0; mf < 4; ++mf)
#pragma unroll
      for (int nf = 0; nf < 2; ++nf)
#pragma unroll
        for (int ks = 0; ks < 2; ++ks)
          acc[mf][nf + 2] = __builtin_amdgcn_mfma_f32_16x16x32_f16(
              af[mf][ks], bfH[nf][ks], acc[mf][nf + 2], 0, 0, 0);
    __builtin_amdgcn_s_setprio(0);
    asm volatile("s_waitcnt vmcnt(4)" ::: "memory");  // gate Q2's af(h1)
    __builtin_amdgcn_s_barrier();
    __builtin_amdgcn_sched_barrier(0);

    // ======== Q2: rows wm+64..+127 x cols wn..+31 (reuse bfL) ========
#pragma unroll
    for (int mf = 0; mf < 4; ++mf)
#pragma unroll
      for (int ks = 0; ks < 2; ++ks)
        af[mf][ks] = *(const halfv8*)&As[cur][aidx(wm + 64 + mf * 16 + lr, ks * 4 + lk)];
    STG_B(nxt, 1, ktn)
    __builtin_amdgcn_s_barrier();
    __builtin_amdgcn_s_setprio(1);
#pragma unroll
    for (int mf = 0; mf < 4; ++mf)
#pragma unroll
      for (int nf = 0; nf < 2; ++nf)
#pragma unroll
        for (int ks = 0; ks < 2; ++ks)
          acc[mf + 4][nf] = __builtin_amdgcn_mfma_f32_16x16x32_f16(
              af[mf][ks], bfL[nf][ks], acc[mf + 4][nf], 0, 0, 0);
    __builtin_amdgcn_s_setprio(0);
    __builtin_amdgcn_s_barrier();                     // no gate (Q3 reads none)

    // ======== Q3: rows wm+64..+127 x cols wn+32..+63 (reuse af,bfH) ========
    STG_A(nxt, 1, ktn)
    __builtin_amdgcn_s_barrier();
    __builtin_amdgcn_s_setprio(1);
#pragma unroll
    for (int mf = 0; mf < 4; ++mf)
#pragma unroll
      for (int nf = 0; nf < 2; ++nf)
#pragma unroll
        for (int ks = 0; ks < 2; ++ks)
          acc[mf + 4][nf + 2] = __builtin_amdgcn_mfma_f32_16x16x32_f16(
              af[mf][ks], bfH[nf][ks], acc[mf + 4][nf + 2], 0, 0, 0);
    __builtin_amdgcn_s_setprio(0);
    asm volatile("s_waitcnt vmcnt(4)" ::: "memory");  // gate next tile's Q0
    __builtin_amdgcn_s_barrier();
    __builtin_amdgcn_sched_barrier(0);
  }

  // epilogue: fp16 partial store
  half_t* C = Cbase + (size_t)ksz * ((size_t)NBS * HID);
#pragma unroll
  for (int mf = 0; mf < 8; ++mf)
#pragma unroll
    for (int nf = 0; nf < 4; ++nf) {
      const int n = n0 + wn + nf * 16 + lr;
#pragma unroll
      for (int q = 0; q < 4; ++q) {
        const int m = m0 + wm + mf * 16 + lk * 4 + q;
        C[(size_t)m * HID + n] = (half_t)acc[mf][nf][q];
      }
    }
#undef STG_A
#undef STG_B
}

// ---------------------------------------------------------------------------
// head: hidden = relu(sum_ks C[ks] + b1); logits = hidden @ w2^T + b2; softmax
__global__ __launch_bounds__(256) void head(
    const half_t* __restrict__ Cb, const float* __restrict__ b1,
    const float* __restrict__ w2, const float* __restrict__ b2,
    float* __restrict__ out) {
  __shared__ __attribute__((aligned(16))) float w2s[NCLS * HID];
  const int t = threadIdx.x;
  {
    const floatv4* s4 = (const floatv4*)w2;
    floatv4* d4 = (floatv4*)w2s;
    for (int i = t; i < (NCLS * HID) / 4; i += 256) d4[i] = s4[i];
  }
  __syncthreads();
  const int w = t >> 6, l = t & 63;
  const int row = blockIdx.x * 4 + w;

  float r[16];
#pragma unroll
  for (int jj = 0; jj < 4; ++jj) {
    floatv4 bb = *(const floatv4*)&b1[jj * 256 + l * 4];
    float s[4] = {bb[0], bb[1], bb[2], bb[3]};
#pragma unroll
    for (int p = 0; p < KS; ++p) {
      const half_t* cp = Cb + (size_t)p * ((size_t)NBS * HID) + (size_t)row * HID;
      halfv4 u = *(const halfv4*)&cp[jj * 256 + l * 4];
#pragma unroll
      for (int q = 0; q < 4; ++q) s[q] += (float)u[q];
    }
#pragma unroll
    for (int q = 0; q < 4; ++q) r[jj * 4 + q] = s[q] > 0.f ? s[q] : 0.f;
  }
  float lg[10];
#pragma unroll
  for (int c = 0; c < NCLS; ++c) {
    float p = 0.f;
#pragma unroll
    for (int jj = 0; jj < 4; ++jj) {
      floatv4 wv = *(const floatv4*)&w2s[c * HID + jj * 256 + l * 4];
      p += r[jj * 4 + 0] * wv[0] + r[jj * 4 + 1] * wv[1] +
           r[jj * 4 + 2] * wv[2] + r[jj * 4 + 3] * wv[3];
    }
#pragma unroll
    for (int off = 32; off >= 1; off >>= 1) p += __shfl_xor(p, off);
    lg[c] = p + b2[c];
  }
  float mx = lg[0];
#pragma unroll
  for (int c = 1; c < NCLS; ++c) mx = fmaxf(mx, lg[c]);
  float sum = 0.f;
#pragma unroll
  for (int c = 0; c < NCLS; ++c) { lg[c] = __expf(lg[c] - mx); sum += lg[c]; }
  const float inv = 1.f / sum;
  float myv = 0.f;
#pragma unroll
  for (int c = 0; c < NCLS; ++c) myv = (l == c) ? lg[c] * inv : myv;
  if (l < NCLS) out[(size_t)row * NCLS + l] = myv;
}

// ---------------------------------------------------------------------------
extern "C" void kernel_launch(void* const* d_in, const int* in_sizes, int n_in,
                              void* d_out, int out_size, void* d_ws, size_t ws_size,
                              hipStream_t stream) {
  (void)in_sizes; (void)n_in; (void)out_size; (void)ws_size;
  const float* x  = (const float*)d_in[0];
  const int*   ei = (const int*)d_in[1];
  const float* gw = (const float*)d_in[2];
  const float* gb = (const float*)d_in[3];
  const float* w1 = (const float*)d_in[4];
  const float* b1 = (const float*)d_in[5];
  const float* w2 = (const float*)d_in[6];
  const float* b2 = (const float*)d_in[7];
  float* out = (float*)d_out;

  char* ws = (char*)d_ws;
  half_t* H    = (half_t*)(ws);                        // 32 MB
  half_t* C    = (half_t*)(ws + 33554432);             // KS x 8 MB = 32 MB
  half_t* w1p  = (half_t*)(ws + 67108864);             //  8 MB
  half_t* gw16 = (half_t*)(ws + 75497472);             // 32 KB

  prep_cvt <<<dim3(4112),    dim3(256), 0, stream>>>(w1, w1p, gw, gw16);
  gin_fused<<<dim3(NBS / 4), dim3(256), 0, stream>>>(x, ei, gw16, gb, H);
  lin1_gemm<<<dim3(16 * 4 * KS), dim3(512), 0, stream>>>(H, w1p, C);
  head     <<<dim3(NBS / 4), dim3(256), 0, stream>>>(C, b1, w2, b2, out);
}

// Round 17
// 80.642 us; speedup vs baseline: 1.1057x; 1.1057x over previous
//
#include <hip/hip_runtime.h>

typedef _Float16 half_t;
typedef _Float16 halfv8 __attribute__((ext_vector_type(8)));
typedef _Float16 halfv4 __attribute__((ext_vector_type(4)));
typedef float    floatv4 __attribute__((ext_vector_type(4)));
typedef unsigned int uint;
typedef uint uintv4 __attribute__((ext_vector_type(4)));

#define NODES 32
#define FIN   128
#define EPG   512
#define NBS   4096
#define ETOT  (NBS*EPG)
#define HID   1024
#define KDIM  4096          // FIN*NODES
#define NCLS  10
#define YP    36            // pitch (halves) for Z^T / H^T bounce
#define WP    140           // pitch (halves) for W in LDS

// lin1 GEMM geometry
#define BM 256
#define BN 256
#define BK 64
#define KS 4
#define KSLEN (KDIM/KS)  // 1024
#define NT (KSLEN/BK)    // 16 K-tiles

#define GLDS16(g, l)                                                        \
  __builtin_amdgcn_global_load_lds(                                         \
      (const __attribute__((address_space(1))) unsigned int*)(g),           \
      (__attribute__((address_space(3))) unsigned int*)(l), 16, 0, 0)

// LDS index maps (halves). A layout: [r>>7][ (r>>6)&1 ][r&63][chunk^(r&7)]
__device__ __forceinline__ int aidx(int r, int cc) {
  return (r >> 7) * 8192 + ((r >> 6) & 1) * 4096 + (r & 63) * 64 +
         ((cc ^ (r & 7)) * 8);
}
// B layout: [r>>7][ (r>>5)&1 ][ (r>>6)&1 ][r&31][chunk^(r&7)]
__device__ __forceinline__ int bidx(int r, int cc) {
  return (r >> 7) * 8192 + ((r >> 5) & 1) * 4096 + ((r >> 6) & 1) * 2048 +
         (r & 31) * 64 + ((cc ^ (r & 7)) * 8);
}

// ---------------------------------------------------------------------------
// prep: pure fp32->fp16 casts (H layout [g][o*32+m] matches original w1).
__global__ __launch_bounds__(256) void prep_cvt(const float* __restrict__ w1,
                                                half_t* __restrict__ w1p,
                                                const float* __restrict__ gw,
                                                half_t* __restrict__ gw16) {
  const size_t q = (size_t)blockIdx.x * 256 + threadIdx.x;  // 1052672 quads
  const float* s;
  half_t* d;
  size_t off;
  if (q < 1048576) { s = w1; d = w1p; off = q; }
  else             { s = gw; d = gw16; off = q - 1048576; }
  floatv4 v = *(const floatv4*)(s + off * 4);
  halfv4 h = {(half_t)v[0], (half_t)v[1], (half_t)v[2], (half_t)v[3]};
  *(halfv4*)(d + off * 4) = h;
}

// ---------------------------------------------------------------------------
// gin_fused v6 (measured-best ~33-35 us): W block-staged in LDS (separate
// buffer, VGPR 88 keeps batched x-prefetch live); Z^T/H^T LDS bounce;
// fat coalesced H stores. 80.9 KB LDS, 2 blocks/CU.
__global__ __launch_bounds__(256, 2) void gin_fused(
    const float* __restrict__ x, const int* __restrict__ ei,
    const half_t* __restrict__ gw16, const float* __restrict__ gb,
    half_t* __restrict__ H) {
  __shared__ __attribute__((aligned(16))) half_t Ws[FIN * WP];     // 35840 B
  __shared__ __attribute__((aligned(16))) half_t Yt[4][FIN * YP];  // 36864 B
  __shared__ uint cnt[4][512];                                     //  8192 B

  const int t = threadIdx.x, w = t >> 6, l = t & 63;
  const int lr = l & 15, lk = l >> 4;
  const int g = blockIdx.x * 4 + w;

  const float* xg = x + (size_t)g * (NODES * FIN);
  floatv4 xr[2][4][2];
#pragma unroll
  for (int mt = 0; mt < 2; ++mt)
#pragma unroll
    for (int kk = 0; kk < 4; ++kk) {
      const float* p = xg + (mt * 16 + lr) * FIN + kk * 32 + lk * 8;
      xr[mt][kk][0] = *(const floatv4*)p;
      xr[mt][kk][1] = *(const floatv4*)(p + 4);
    }

  {
    const halfv8* gsrc = (const halfv8*)gw16;
#pragma unroll
    for (int i = 0; i < 8; ++i) {
      const int c = i * 256 + t;
      const int o = c >> 4, f8 = c & 15;
      *(halfv8*)&Ws[o * WP + f8 * 8] = gsrc[c];
    }
  }

  const int* sp = ei + (size_t)g * EPG;
  const int* dp = ei + (size_t)ETOT + (size_t)g * EPG;
  uintv4 s0 = *(const uintv4*)(sp + l * 8);
  uintv4 s1 = *(const uintv4*)(sp + l * 8 + 4);
  uintv4 d0 = *(const uintv4*)(dp + l * 8);
  uintv4 d1 = *(const uintv4*)(dp + l * 8 + 4);

  {
    uintv4* c4 = (uintv4*)cnt[w];
    uintv4 z = {0, 0, 0, 0};
    c4[l] = z;
    c4[l + 64] = z;
  }
#pragma unroll
  for (int q = 0; q < 4; ++q) {
    uint p0 = (d0[q] & 31) * 32 + (s0[q] & 31);
    atomicAdd(&cnt[w][p0 >> 1], 1u << ((p0 & 1) * 16));
    uint p1 = (d1[q] & 31) * 32 + (s1[q] & 31);
    atomicAdd(&cnt[w][p1 >> 1], 1u << ((p1 & 1) * 16));
  }

  halfv8 af[2][4];
#pragma unroll
  for (int mt = 0; mt < 2; ++mt)
#pragma unroll
    for (int kk = 0; kk < 4; ++kk) {
      halfv8 h;
#pragma unroll
      for (int q = 0; q < 4; ++q) {
        h[q]     = (half_t)xr[mt][kk][0][q];
        h[q + 4] = (half_t)xr[mt][kk][1][q];
      }
      af[mt][kk] = h;
    }

  __syncthreads();   // Ws staged (cross-wave)

  floatv4 acc[2][8] = {};
#pragma unroll
  for (int kk = 0; kk < 4; ++kk) {
    halfv8 bfk[8];
#pragma unroll
    for (int nt = 0; nt < 8; ++nt)
      bfk[nt] = *(const halfv8*)&Ws[(nt * 16 + lr) * WP + kk * 32 + lk * 8];
#pragma unroll
    for (int nt = 0; nt < 8; ++nt)
#pragma unroll
      for (int mt = 0; mt < 2; ++mt)
        acc[mt][nt] = __builtin_amdgcn_mfma_f32_16x16x32_f16(af[mt][kk], bfk[nt],
                                                             acc[mt][nt], 0, 0, 0);
  }
  __builtin_amdgcn_sched_barrier(0);

  half_t* yw = Yt[w];
#pragma unroll
  for (int mt = 0; mt < 2; ++mt)
#pragma unroll
    for (int nt = 0; nt < 8; ++nt) {
      halfv4 h = {(half_t)acc[mt][nt][0], (half_t)acc[mt][nt][1],
                  (half_t)acc[mt][nt][2], (half_t)acc[mt][nt][3]};
      *(halfv4*)&yw[(nt * 16 + lr) * YP + mt * 16 + lk * 4] = h;
    }

  const unsigned short* c16 = (const unsigned short*)cnt[w];
  halfv8 am[2];
#pragma unroll
  for (int mt = 0; mt < 2; ++mt) {
    const int i = mt * 16 + lr;
#pragma unroll
    for (int q = 0; q < 8; ++q) {
      const int j = lk * 8 + q;
      float c = (float)c16[i * 32 + j] + ((j == i) ? 1.f : 0.f);
      am[mt][q] = (half_t)c;
    }
  }

  floatv4 acc2[2][8] = {};
#pragma unroll
  for (int nt = 0; nt < 8; ++nt) {
    halfv8 bf = *(const halfv8*)&yw[(nt * 16 + lr) * YP + lk * 8];
#pragma unroll
    for (int mt = 0; mt < 2; ++mt)
      acc2[mt][nt] = __builtin_amdgcn_mfma_f32_16x16x32_f16(am[mt], bf,
                                                            acc2[mt][nt], 0, 0, 0);
  }
  __builtin_amdgcn_sched_barrier(0);

#pragma unroll
  for (int nt = 0; nt < 8; ++nt) {
    const float bias = gb[nt * 16 + lr];
#pragma unroll
    for (int mt = 0; mt < 2; ++mt) {
      halfv4 h;
#pragma unroll
      for (int q = 0; q < 4; ++q) {
        const float v = acc2[mt][nt][q] + bias;
        h[q] = (half_t)(v > 0.f ? v : 0.f);
      }
      *(halfv4*)&yw[(nt * 16 + lr) * YP + mt * 16 + lk * 4] = h;
    }
  }
  __builtin_amdgcn_sched_barrier(0);

  half_t* Hg = H + (size_t)g * KDIM;
#pragma unroll
  for (int c = 0; c < 8; ++c) {
    const int ch = c * 64 + l;
    const int o = ch >> 2, m0 = (ch & 3) * 8;
    halfv8 v = *(const halfv8*)&yw[o * YP + m0];
    *(halfv8*)(Hg + ch * 8) = v;
  }
}

// ---------------------------------------------------------------------------
// lin1 GEMM: quadrant-phase pipeline (measured-best 38.7 us, r15 verbatim).
// 4 quadrant-phases/K-tile, each stages one future half; vmcnt(4) gates at
// ends of Q0/Q1/Q3 (cross-wave-correct: gate precedes the closing barrier);
// lgkmcnt(0)+sched_barrier after opening barriers; setprio on MFMA clusters.
__global__ __launch_bounds__(512, 2) void lin1_gemm(
    const half_t* __restrict__ A, const half_t* __restrict__ B,
    half_t* __restrict__ Cbase) {
  __shared__ __attribute__((aligned(16))) half_t As[2][16384];  // 64 KB
  __shared__ __attribute__((aligned(16))) half_t Bs[2][16384];  // 64 KB

  const int t = threadIdx.x;
  const int orig = blockIdx.x;                     // 256 blocks, 1/CU
  const int wg = (orig & 7) * 32 + (orig >> 3);    // bijective XCD swizzle
  const int mt = wg & 15, rest = wg >> 4;
  const int nt_ = rest & 3, ksz = rest >> 2;
  const int m0 = mt * BM, n0 = nt_ * BN, k0 = ksz * KSLEN;

  const int csw = ((t & 7) ^ ((t >> 3) & 7)) * 8;
  const int ar0 = t >> 3;
  const int brl = (t >> 3) & 31, bg = t >> 8;
  const half_t* pA[2][2];
  const half_t* pB[2][2];
#pragma unroll
  for (int h = 0; h < 2; ++h) {
    pA[h][0] = A + (size_t)(m0 + ar0 + h * 64) * KDIM + k0 + csw;
    pA[h][1] = pA[h][0] + (size_t)128 * KDIM;
    pB[h][0] = B + (size_t)(n0 + bg * 64 + h * 32 + brl) * KDIM + k0 + csw;
    pB[h][1] = pB[h][0] + (size_t)128 * KDIM;
  }

#define STG_A(buf, h, kt_)                                                   \
  { GLDS16(pA[h][0] + (kt_) * BK, &As[buf][(h) * 4096 + t * 8]);             \
    GLDS16(pA[h][1] + (kt_) * BK, &As[buf][8192 + (h) * 4096 + t * 8]); }
#define STG_B(buf, h, kt_)                                                   \
  { GLDS16(pB[h][0] + (kt_) * BK, &Bs[buf][(h) * 4096 + t * 8]);             \
    GLDS16(pB[h][1] + (kt_) * BK, &Bs[buf][8192 + (h) * 4096 + t * 8]); }

  const int w = t >> 6, l = t & 63, lr = l & 15, lk = l >> 4;
  const int wm = (w >> 2) * 128, wn = (w & 3) * 64;

  floatv4 acc[8][4] = {};

  // prologue: tile 0's 4 halves; gate h0A/h0B (newer = 4 loads)
  STG_A(0, 0, 0) STG_B(0, 0, 0) STG_B(0, 1, 0) STG_A(0, 1, 0)
  asm volatile("s_waitcnt vmcnt(4)" ::: "memory");
  __builtin_amdgcn_s_barrier();

  for (int kt = 0; kt < NT; ++kt) {
    const int cur = kt & 1, nxt = cur ^ 1;
    const int ktn = (kt + 1 < NT) ? (kt + 1) : 0;  // dummy tail keeps counts uniform
    halfv8 af[4][2], bfL[2][2], bfH[2][2];

    // ======== Q0: rows wm..+63 x cols wn..+31, K=64 ========
#pragma unroll
    for (int mf = 0; mf < 4; ++mf)
#pragma unroll
      for (int ks = 0; ks < 2; ++ks)
        af[mf][ks] = *(const halfv8*)&As[cur][aidx(wm + mf * 16 + lr, ks * 4 + lk)];
#pragma unroll
    for (int nf = 0; nf < 2; ++nf)
#pragma unroll
      for (int ks = 0; ks < 2; ++ks)
        bfL[nf][ks] = *(const halfv8*)&Bs[cur][bidx(wn + nf * 16 + lr, ks * 4 + lk)];
    STG_A(nxt, 0, ktn)
    __builtin_amdgcn_s_barrier();
    asm volatile("s_waitcnt lgkmcnt(0)" ::: "memory");
    __builtin_amdgcn_sched_barrier(0);
    __builtin_amdgcn_s_setprio(1);
#pragma unroll
    for (int mf = 0; mf < 4; ++mf)
#pragma unroll
      for (int nf = 0; nf < 2; ++nf)
#pragma unroll
        for (int ks = 0; ks < 2; ++ks)
          acc[mf][nf] = __builtin_amdgcn_mfma_f32_16x16x32_f16(
              af[mf][ks], bfL[nf][ks], acc[mf][nf], 0, 0, 0);
    __builtin_amdgcn_s_setprio(0);
    asm volatile("s_waitcnt vmcnt(4)" ::: "memory");  // gate Q1's bfH
    __builtin_amdgcn_s_barrier();

    // ======== Q1: rows wm..+63 x cols wn+32..+63 ========
#pragma unroll
    for (int nf = 0; nf < 2; ++nf)
#pragma unroll
      for (int ks = 0; ks < 2; ++ks)
        bfH[nf][ks] = *(const halfv8*)&Bs[cur][bidx(wn + 32 + nf * 16 + lr, ks * 4 + lk)];
    STG_B(nxt, 0, ktn)
    __builtin_amdgcn_s_barrier();
    asm volatile("s_waitcnt lgkmcnt(0)" ::: "memory");
    __builtin_amdgcn_sched_barrier(0);
    __builtin_amdgcn_s_setprio(1);
#pragma unroll
    for (int mf = 0; mf < 4; ++mf)
#pragma unroll
      for (int nf = 0; nf < 2; ++nf)
#pragma unroll
        for (int ks = 0; ks < 2; ++ks)
          acc[mf][nf + 2] = __builtin_amdgcn_mfma_f32_16x16x32_f16(
              af[mf][ks], bfH[nf][ks], acc[mf][nf + 2], 0, 0, 0);
    __builtin_amdgcn_s_setprio(0);
    asm volatile("s_waitcnt vmcnt(4)" ::: "memory");  // gate Q2's af(h1)
    __builtin_amdgcn_s_barrier();

    // ======== Q2: rows wm+64..+127 x cols wn..+31 (reuse bfL) ========
#pragma unroll
    for (int mf = 0; mf < 4; ++mf)
#pragma unroll
      for (int ks = 0; ks < 2; ++ks)
        af[mf][ks] = *(const halfv8*)&As[cur][aidx(wm + 64 + mf * 16 + lr, ks * 4 + lk)];
    STG_B(nxt, 1, ktn)
    __builtin_amdgcn_s_barrier();
    asm volatile("s_waitcnt lgkmcnt(0)" ::: "memory");
    __builtin_amdgcn_sched_barrier(0);
    __builtin_amdgcn_s_setprio(1);
#pragma unroll
    for (int mf = 0; mf < 4; ++mf)
#pragma unroll
      for (int nf = 0; nf < 2; ++nf)
#pragma unroll
        for (int ks = 0; ks < 2; ++ks)
          acc[mf + 4][nf] = __builtin_amdgcn_mfma_f32_16x16x32_f16(
              af[mf][ks], bfL[nf][ks], acc[mf + 4][nf], 0, 0, 0);
    __builtin_amdgcn_s_setprio(0);
    __builtin_amdgcn_s_barrier();                     // no gate (Q3 reads none)

    // ======== Q3: rows wm+64..+127 x cols wn+32..+63 (reuse af,bfH) ========
    STG_A(nxt, 1, ktn)
    __builtin_amdgcn_s_barrier();
    __builtin_amdgcn_sched_barrier(0);
    __builtin_amdgcn_s_setprio(1);
#pragma unroll
    for (int mf = 0; mf < 4; ++mf)
#pragma unroll
      for (int nf = 0; nf < 2; ++nf)
#pragma unroll
        for (int ks = 0; ks < 2; ++ks)
          acc[mf + 4][nf + 2] = __builtin_amdgcn_mfma_f32_16x16x32_f16(
              af[mf][ks], bfH[nf][ks], acc[mf + 4][nf + 2], 0, 0, 0);
    __builtin_amdgcn_s_setprio(0);
    asm volatile("s_waitcnt vmcnt(4)" ::: "memory");  // gate next tile's Q0
    __builtin_amdgcn_s_barrier();
  }

  // epilogue: fp16 partial store
  half_t* C = Cbase + (size_t)ksz * ((size_t)NBS * HID);
#pragma unroll
  for (int mf = 0; mf < 8; ++mf)
#pragma unroll
    for (int nf = 0; nf < 4; ++nf) {
      const int n = n0 + wn + nf * 16 + lr;
#pragma unroll
      for (int q = 0; q < 4; ++q) {
        const int m = m0 + wm + mf * 16 + lk * 4 + q;
        C[(size_t)m * HID + n] = (half_t)acc[mf][nf][q];
      }
    }
#undef STG_A
#undef STG_B
}

// ---------------------------------------------------------------------------
// head: hidden = relu(sum_ks C[ks] + b1); logits = hidden @ w2^T + b2; softmax
__global__ __launch_bounds__(256) void head(
    const half_t* __restrict__ Cb, const float* __restrict__ b1,
    const float* __restrict__ w2, const float* __restrict__ b2,
    float* __restrict__ out) {
  __shared__ __attribute__((aligned(16))) float w2s[NCLS * HID];
  const int t = threadIdx.x;
  {
    const floatv4* s4 = (const floatv4*)w2;
    floatv4* d4 = (floatv4*)w2s;
    for (int i = t; i < (NCLS * HID) / 4; i += 256) d4[i] = s4[i];
  }
  __syncthreads();
  const int w = t >> 6, l = t & 63;
  const int row = blockIdx.x * 4 + w;

  float r[16];
#pragma unroll
  for (int jj = 0; jj < 4; ++jj) {
    floatv4 bb = *(const floatv4*)&b1[jj * 256 + l * 4];
    float s[4] = {bb[0], bb[1], bb[2], bb[3]};
#pragma unroll
    for (int p = 0; p < KS; ++p) {
      const half_t* cp = Cb + (size_t)p * ((size_t)NBS * HID) + (size_t)row * HID;
      halfv4 u = *(const halfv4*)&cp[jj * 256 + l * 4];
#pragma unroll
      for (int q = 0; q < 4; ++q) s[q] += (float)u[q];
    }
#pragma unroll
    for (int q = 0; q < 4; ++q) r[jj * 4 + q] = s[q] > 0.f ? s[q] : 0.f;
  }
  float lg[10];
#pragma unroll
  for (int c = 0; c < NCLS; ++c) {
    float p = 0.f;
#pragma unroll
    for (int jj = 0; jj < 4; ++jj) {
      floatv4 wv = *(const floatv4*)&w2s[c * HID + jj * 256 + l * 4];
      p += r[jj * 4 + 0] * wv[0] + r[jj * 4 + 1] * wv[1] +
           r[jj * 4 + 2] * wv[2] + r[jj * 4 + 3] * wv[3];
    }
#pragma unroll
    for (int off = 32; off >= 1; off >>= 1) p += __shfl_xor(p, off);
    lg[c] = p + b2[c];
  }
  float mx = lg[0];
#pragma unroll
  for (int c = 1; c < NCLS; ++c) mx = fmaxf(mx, lg[c]);
  float sum = 0.f;
#pragma unroll
  for (int c = 0; c < NCLS; ++c) { lg[c] = __expf(lg[c] - mx); sum += lg[c]; }
  const float inv = 1.f / sum;
  float myv = 0.f;
#pragma unroll
  for (int c = 0; c < NCLS; ++c) myv = (l == c) ? lg[c] * inv : myv;
  if (l < NCLS) out[(size_t)row * NCLS + l] = myv;
}

// ---------------------------------------------------------------------------
extern "C" void kernel_launch(void* const* d_in, const int* in_sizes, int n_in,
                              void* d_out, int out_size, void* d_ws, size_t ws_size,
                              hipStream_t stream) {
  (void)in_sizes; (void)n_in; (void)out_size; (void)ws_size;
  const float* x  = (const float*)d_in[0];
  const int*   ei = (const int*)d_in[1];
  const float* gw = (const float*)d_in[2];
  const float* gb = (const float*)d_in[3];
  const float* w1 = (const float*)d_in[4];
  const float* b1 = (const float*)d_in[5];
  const float* w2 = (const float*)d_in[6];
  const float* b2 = (const float*)d_in[7];
  float* out = (float*)d_out;

  char* ws = (char*)d_ws;
  half_t* H    = (half_t*)(ws);                        // 32 MB
  half_t* C    = (half_t*)(ws + 33554432);             // KS x 8 MB = 32 MB
  half_t* w1p  = (half_t*)(ws + 67108864);             //  8 MB
  half_t* gw16 = (half_t*)(ws + 75497472);             // 32 KB

  prep_cvt <<<dim3(4112),    dim3(256), 0, stream>>>(w1, w1p, gw, gw16);
  gin_fused<<<dim3(NBS / 4), dim3(256), 0, stream>>>(x, ei, gw16, gb, H);
  lin1_gemm<<<dim3(16 * 4 * KS), dim3(512), 0, stream>>>(H, w1p, C);
  head     <<<dim3(NBS / 4), dim3(256), 0, stream>>>(C, b1, w2, b2, out);
}